// Round 4
// baseline (585.564 us; speedup 1.0000x reference)
//
#include <hip/hip_runtime.h>
#include <cmath>

// Problem constants: B=1024, IN=1024, OUT=1024, K=100
#define KSAMP 100
#define DIN   1024
#define DOUT  1024
#define DB    1024

typedef float f4 __attribute__((ext_vector_type(4)));  // native vec for nontemporal

// ---------------------------------------------------------------------------
// Kernel 1: W_eff[i][j] = mean_k(eps[k][i][j]) * softplus(ws[i][j]) + wm[i][j]
// Pure HBM stream of eps (419 MB read). 1024 blocks x 256 thr, float4/lane,
// 20 loads in flight (unroll 10 x 2 chains). Model: ~67 us at 6.3 TB/s.
// ---------------------------------------------------------------------------
__global__ __launch_bounds__(256) void weff_kernel(
    const f4* __restrict__ eps,
    const f4* __restrict__ wm,
    const f4* __restrict__ ws,
    f4* __restrict__ weff)
{
    const int idx = blockIdx.x * blockDim.x + threadIdx.x;   // 0..262143
    const int n4 = (DIN * DOUT) / 4;

    f4 acc0 = {0.f, 0.f, 0.f, 0.f};
    f4 acc1 = {0.f, 0.f, 0.f, 0.f};
    const f4* p = eps + idx;
    #pragma unroll 10
    for (int k = 0; k < KSAMP; k += 2) {
        f4 e0 = __builtin_nontemporal_load(p);
        f4 e1 = __builtin_nontemporal_load(p + n4);
        p += 2 * n4;
        acc0 += e0;
        acc1 += e1;
    }
    f4 sum = acc0 + acc1;

    f4 s = ws[idx];
    f4 m = wm[idx];
    const float invK = 1.0f / (float)KSAMP;

    // softplus(v) = max(v,0) + log1p(exp(-|v|))  (numerically stable)
    f4 sp;
    sp.x = fmaxf(s.x, 0.f) + log1pf(expf(-fabsf(s.x)));
    sp.y = fmaxf(s.y, 0.f) + log1pf(expf(-fabsf(s.y)));
    sp.z = fmaxf(s.z, 0.f) + log1pf(expf(-fabsf(s.z)));
    sp.w = fmaxf(s.w, 0.f) + log1pf(expf(-fabsf(s.w)));

    f4 o;
    o.x = fmaf(sum.x * invK, sp.x, m.x);
    o.y = fmaf(sum.y * invK, sp.y, m.y);
    o.z = fmaf(sum.z * invK, sp.z, m.z);
    o.w = fmaf(sum.w * invK, sp.w, m.w);
    weff[idx] = o;
}

// ---------------------------------------------------------------------------
// Kernel 2: split-K fp32 GEMM, partials to workspace (no atomics).
// 128x128 tile, 256 threads, 8x8 micro-tile, BK=16 (8 K-iters, 16 KB LDS),
// KSPLIT=8 -> 512 blocks = 2 blocks/CU. Register prefetch of next tile.
// Pure-FMA floor: 2.15 GFLOP -> 13.7 us; predict ~18-22 us.
// ---------------------------------------------------------------------------
#define BM 128
#define BN 128
#define BK 16
#define KSPLIT 8

__global__ __launch_bounds__(256, 2) void sgemm_splitk(
    const float* __restrict__ A,   // x      [DB,  DIN]
    const float* __restrict__ B,   // W_eff  [DIN, DOUT]
    float* __restrict__ P)         // partials [KSPLIT][DB][DOUT]
{
    __shared__ float As[BK][BM];   // k-major (A transposed in LDS)
    __shared__ float Bs[BK][BN];

    const int bx = blockIdx.x, by = blockIdx.y, kz = blockIdx.z;
    const int tid = threadIdx.x;
    const int tx = tid & 15;       // 8 output cols each
    const int ty = tid >> 4;       // 8 output rows each

    const int kc = DIN / KSPLIT;   // 128
    const int k_begin = kz * kc;

    // A load map: row = tid>>1 (0..127), k-offset = (tid&1)*8 (two float4)
    const int arow = tid >> 1;
    const int acol = (tid & 1) * 8;
    // B load map: krow = tid>>4 (0..15), col = (tid&15)*8 (two float4)
    const int brow = tid >> 4;
    const int bcol = (tid & 15) * 8;

    const float* Aptr = &A[(size_t)(by * BM + arow) * DIN + k_begin + acol];
    const float* Bptr = &B[(size_t)(k_begin + brow) * DOUT + bx * BN + bcol];

    float acc[8][8];
    #pragma unroll
    for (int i = 0; i < 8; ++i)
        #pragma unroll
        for (int j = 0; j < 8; ++j) acc[i][j] = 0.f;

    // Preload first tile into registers
    float4 a0 = *(const float4*)(Aptr + 0);
    float4 a1 = *(const float4*)(Aptr + 4);
    float4 b0 = *(const float4*)(Bptr + 0);
    float4 b1 = *(const float4*)(Bptr + 4);

    const int niter = kc / BK;     // 8
    for (int it = 0; it < niter; ++it) {
        __syncthreads();           // previous iteration's LDS reads done
        As[acol + 0][arow] = a0.x;
        As[acol + 1][arow] = a0.y;
        As[acol + 2][arow] = a0.z;
        As[acol + 3][arow] = a0.w;
        As[acol + 4][arow] = a1.x;
        As[acol + 5][arow] = a1.y;
        As[acol + 6][arow] = a1.z;
        As[acol + 7][arow] = a1.w;
        *(float4*)&Bs[brow][bcol + 0] = b0;
        *(float4*)&Bs[brow][bcol + 4] = b1;
        __syncthreads();           // tile visible

        // Prefetch next tile while computing this one
        if (it + 1 < niter) {
            const float* An = Aptr + (it + 1) * BK;
            const float* Bn = Bptr + (size_t)(it + 1) * BK * DOUT;
            a0 = *(const float4*)(An + 0);
            a1 = *(const float4*)(An + 4);
            b0 = *(const float4*)(Bn + 0);
            b1 = *(const float4*)(Bn + 4);
        }

        #pragma unroll
        for (int kk = 0; kk < BK; ++kk) {
            float4 ra0 = *(const float4*)&As[kk][ty * 8];
            float4 ra1 = *(const float4*)&As[kk][ty * 8 + 4];
            float4 rb0 = *(const float4*)&Bs[kk][tx * 8];
            float4 rb1 = *(const float4*)&Bs[kk][tx * 8 + 4];
            const float ar[8] = {ra0.x, ra0.y, ra0.z, ra0.w, ra1.x, ra1.y, ra1.z, ra1.w};
            const float br[8] = {rb0.x, rb0.y, rb0.z, rb0.w, rb1.x, rb1.y, rb1.z, rb1.w};
            #pragma unroll
            for (int i = 0; i < 8; ++i)
                #pragma unroll
                for (int j = 0; j < 8; ++j)
                    acc[i][j] = fmaf(ar[i], br[j], acc[i][j]);
        }
    }

    // Plain float4 stores to this split's partial buffer
    float* Pz = P + (size_t)kz * DB * DOUT;
    #pragma unroll
    for (int i = 0; i < 8; ++i) {
        const int r = by * BM + ty * 8 + i;
        float* prow = &Pz[(size_t)r * DOUT + bx * BN + tx * 8];
        *(float4*)&prow[0] = make_float4(acc[i][0], acc[i][1], acc[i][2], acc[i][3]);
        *(float4*)&prow[4] = make_float4(acc[i][4], acc[i][5], acc[i][6], acc[i][7]);
    }
}

// ---------------------------------------------------------------------------
// Kernel 3: sum the KSPLIT partial buffers into d_out. ~36 MB read, mostly
// L2/L3-resident (just written). Model: ~6 us.
// ---------------------------------------------------------------------------
__global__ __launch_bounds__(256) void reduce_kernel(
    const f4* __restrict__ P, f4* __restrict__ out)
{
    const int idx = blockIdx.x * blockDim.x + threadIdx.x;  // 0..262143
    const int n4 = (DB * DOUT) / 4;
    f4 s = P[idx];
    #pragma unroll
    for (int z = 1; z < KSPLIT; ++z) {
        s += P[(size_t)z * n4 + idx];
    }
    out[idx] = s;
}

// ---------------------------------------------------------------------------
extern "C" void kernel_launch(void* const* d_in, const int* in_sizes, int n_in,
                              void* d_out, int out_size, void* d_ws, size_t ws_size,
                              hipStream_t stream) {
    const float* x   = (const float*)d_in[0];   // [1024,1024]
    const float* eps = (const float*)d_in[1];   // [100,1024,1024]
    const float* wm  = (const float*)d_in[2];   // [1024,1024]
    const float* ws  = (const float*)d_in[3];   // [1024,1024]

    float* weff     = (float*)d_ws;                          // 4 MB
    float* partials = (float*)d_ws + (size_t)DIN * DOUT;     // 8 x 4 MB

    weff_kernel<<<(DIN * DOUT / 4) / 256, 256, 0, stream>>>(
        (const f4*)eps, (const f4*)wm, (const f4*)ws, (f4*)weff);

    sgemm_splitk<<<dim3(DOUT / BN, DB / BM, KSPLIT), 256, 0, stream>>>(
        x, weff, partials);

    reduce_kernel<<<(DB * DOUT / 4) / 256, 256, 0, stream>>>(
        (const f4*)partials, (f4*)d_out);
}